// Round 1
// baseline (68.979 us; speedup 1.0000x reference)
//
#include <hip/hip_runtime.h>
#include <math.h>

#define K 101

// out[p][q] = max_{u,v in [-50,50]} input[q+u, p+v] - (u^2+v^2)/(4*scale)
// Separable: pass A along input columns (v), pass B along rows of A (u).
// Block p computes A-column p then output row p. Input (40 KB) staged in LDS.
__global__ __launch_bounds__(256) void dilation2d_kernel(const float* __restrict__ in,
                                                         const float* __restrict__ scale_p,
                                                         float* __restrict__ out) {
    __shared__ float s_in[K * K];
    __shared__ float s_col[K];

    const int p = blockIdx.x;    // output row index == A-column index
    const int t = threadIdx.x;
    const float inv4s = 1.0f / (4.0f * scale_p[0]);

    // Stage full input into LDS (coalesced, ~40 loads/thread, L2-resident)
    for (int i = t; i < K * K; i += 256) s_in[i] = in[i];
    __syncthreads();

    // Pass A (column p of A): A[r][p] = max_v in[r][p+v] - v^2/(4s)
    if (t < K) {
        const int r = t;
        const int vlo = (p > 50) ? (-50) : (-p);          // p+v >= 0
        const int vhi = (100 - p > 50) ? 50 : (100 - p);  // p+v <= 100
        const float* row = &s_in[r * K + p];
        float best = -INFINITY;
        for (int v = vlo; v <= vhi; ++v) {
            float val = row[v] - (float)(v * v) * inv4s;
            best = fmaxf(best, val);
        }
        s_col[r] = best;
    }
    __syncthreads();

    // Pass B: out[p][q] = max_u A[q+u][p] - u^2/(4s)   (contiguous row write)
    if (t < K) {
        const int q = t;
        const int ulo = (q > 50) ? (-50) : (-q);
        const int uhi = (100 - q > 50) ? 50 : (100 - q);
        float best = -INFINITY;
        for (int u = ulo; u <= uhi; ++u) {
            float val = s_col[q + u] - (float)(u * u) * inv4s;
            best = fmaxf(best, val);
        }
        out[p * K + q] = best;
    }
}

extern "C" void kernel_launch(void* const* d_in, const int* in_sizes, int n_in,
                              void* d_out, int out_size, void* d_ws, size_t ws_size,
                              hipStream_t stream) {
    const float* in    = (const float*)d_in[0];
    const float* scale = (const float*)d_in[1];
    float* out         = (float*)d_out;
    dilation2d_kernel<<<K, 256, 0, stream>>>(in, scale, out);
}

// Round 2
// 59.717 us; speedup vs baseline: 1.1551x; 1.1551x over previous
//
#include <hip/hip_runtime.h>
#include <math.h>

#define K 101
#define KK (K * K)

// out[p][q] = max_{u,v in [-50,50]} input[q+u, p+v] - (u^2+v^2)/(4*scale)
// Separable: pass A over v (within-row offsets), pass B over u.
// Block p computes A-column p then output row p. Input (40 KB) staged in LDS.
// OOB handled by index clamping: clamped candidates are dominated by the
// in-bounds edge candidate (same value, strictly smaller penalty), so no
// -inf padding or variable loop bounds are needed -> constant 101-trip
// fully-unrolled loops with 4 independent max chains.
__global__ __launch_bounds__(256) void dilation2d_kernel(const float* __restrict__ in,
                                                         const float* __restrict__ scale_p,
                                                         float* __restrict__ out) {
    __shared__ float s_in[KK];
    __shared__ float s_col[K];

    const int p = blockIdx.x;   // output row index == A-column index
    const int t = threadIdx.x;
    const float inv4s = 1.0f / (4.0f * scale_p[0]);

    // Stage full input into LDS, vectorized float4 (10201 = 2550*4 + 1).
    {
        const float4* __restrict__ in4 = (const float4*)in;
        float4* s4 = (float4*)s_in;
        #pragma unroll
        for (int i = 0; i < 10; ++i) {
            const int idx = t + i * 256;
            if (idx < KK / 4) s4[idx] = in4[idx];
        }
        if (t == 0) s_in[KK - 1] = in[KK - 1];
    }
    __syncthreads();

    // Pass A: s_col[r] = max_v in[r][clamp(p+v)] - v^2/(4s)
    if (t < K) {
        const float* __restrict__ row = &s_in[t * K];
        float b0 = -INFINITY, b1 = -INFINITY, b2 = -INFINITY, b3 = -INFINITY;
        #pragma unroll
        for (int j = 0; j < K; ++j) {
            const int v = j - 50;
            int c = p + v;
            c = (c < 0) ? 0 : (c > K - 1 ? K - 1 : c);   // v_med3 clamp
            const float val = fmaf((float)(-v * v), inv4s, row[c]);
            if ((j & 3) == 0)      b0 = fmaxf(b0, val);
            else if ((j & 3) == 1) b1 = fmaxf(b1, val);
            else if ((j & 3) == 2) b2 = fmaxf(b2, val);
            else                   b3 = fmaxf(b3, val);
        }
        s_col[t] = fmaxf(fmaxf(b0, b1), fmaxf(b2, b3));
    }
    __syncthreads();

    // Pass B: out[p][q] = max_u s_col[clamp(q+u)] - u^2/(4s)
    if (t < K) {
        const int q = t;
        float b0 = -INFINITY, b1 = -INFINITY, b2 = -INFINITY, b3 = -INFINITY;
        #pragma unroll
        for (int j = 0; j < K; ++j) {
            const int u = j - 50;
            int c = q + u;
            c = (c < 0) ? 0 : (c > K - 1 ? K - 1 : c);
            const float val = fmaf((float)(-u * u), inv4s, s_col[c]);
            if ((j & 3) == 0)      b0 = fmaxf(b0, val);
            else if ((j & 3) == 1) b1 = fmaxf(b1, val);
            else if ((j & 3) == 2) b2 = fmaxf(b2, val);
            else                   b3 = fmaxf(b3, val);
        }
        out[p * K + q] = fmaxf(fmaxf(b0, b1), fmaxf(b2, b3));
    }
}

extern "C" void kernel_launch(void* const* d_in, const int* in_sizes, int n_in,
                              void* d_out, int out_size, void* d_ws, size_t ws_size,
                              hipStream_t stream) {
    const float* in    = (const float*)d_in[0];
    const float* scale = (const float*)d_in[1];
    float* out         = (float*)d_out;
    dilation2d_kernel<<<K, 256, 0, stream>>>(in, scale, out);
}